// Round 1
// baseline (1757.702 us; speedup 1.0000x reference)
//
#include <hip/hip_runtime.h>

#define Bn  2
#define Hn  16
#define Sn  2048
#define DKn 128
#define DVn 128
#define BHn (Bn*Hn)
#define SCALE 0.08838834764831843f  // 1/sqrt(128)

// ---------------------------------------------------------------------------
// Mask dtype detector: int32/float32 0/1 values have byte (4i+1) == 0 always;
// byte-typed bool masks have ~50% nonzero there. Writes 1 = byte mask, 0 = word.
// ---------------------------------------------------------------------------
__global__ void detect_mask_kernel(const unsigned char* __restrict__ m,
                                   int* __restrict__ flag) {
  if (threadIdx.x == 0) {
    int cnt = 0;
    for (int i = 0; i < 4096; ++i) cnt += (m[i * 4 + 1] != 0);
    *flag = (cnt > 0) ? 1 : 0;
  }
}

// ---------------------------------------------------------------------------
// Kernel 1: e = exp(mask ? -inf : Q.K^T * scale), row sums.
// Block: 256 thr, tile = 16 q-rows x 2048 cols (8 col-tiles of 256).
// Thread micro-tile: 4 rows x 4 cols. K staged transposed in LDS (stride 260),
// Q staged transposed (stride 20). rowsum via full-wave shuffle reduce.
// ---------------------------------------------------------------------------
__global__ __launch_bounds__(256) void qk_exp_kernel(
    const float* __restrict__ Q, const float* __restrict__ K,
    const void* __restrict__ mask, const int* __restrict__ mflag,
    float* __restrict__ attn, float* __restrict__ rowsum) {
  const int bh   = blockIdx.y;
  const int b    = bh >> 4;           // H = 16
  const int row0 = blockIdx.x << 4;   // 16 rows / block
  const int t    = threadIdx.x;
  const int rg   = t >> 6;            // 0..3  (== wave id) -> rows rg*4..+3
  const int cg   = t & 63;            // 0..63 -> cols cg*4..+3 within col tile
  const int byteMask = *mflag;

  __shared__ float Qst[128 * 20];     // [d][r], stride 20 (16B-aligned rows)
  __shared__ float Kst[32 * 260];     // [d][j], d-chunk 32, stride 260

  // stage Q tile transposed (once)
  {
    const float4* Qg = (const float4*)(Q + ((size_t)bh * Sn + row0) * DKn);
#pragma unroll
    for (int i = 0; i < 2; ++i) {
      int fid = t + (i << 8);
      int r = fid >> 5, d4 = fid & 31;
      float4 v = Qg[r * 32 + d4];
      Qst[(4 * d4 + 0) * 20 + r] = v.x;
      Qst[(4 * d4 + 1) * 20 + r] = v.y;
      Qst[(4 * d4 + 2) * 20 + r] = v.z;
      Qst[(4 * d4 + 3) * 20 + r] = v.w;
    }
  }

  float psum[4] = {0.f, 0.f, 0.f, 0.f};
  const float4* Kg = (const float4*)(K + (size_t)bh * Sn * DKn);

  for (int jt = 0; jt < 8; ++jt) {
    float acc[4][4];
#pragma unroll
    for (int i = 0; i < 4; ++i)
#pragma unroll
      for (int l = 0; l < 4; ++l) acc[i][l] = 0.f;

    for (int dc = 0; dc < 4; ++dc) {
      __syncthreads();  // protect Kst from previous readers
      // stage K chunk transposed: j = jt*256..+255, d = dc*32..+31
#pragma unroll
      for (int i = 0; i < 8; ++i) {
        int fid = t + (i << 8);     // 0..2047
        int j = fid >> 3, d4 = fid & 7;
        float4 v = Kg[(size_t)(jt * 256 + j) * 32 + dc * 8 + d4];
        Kst[(4 * d4 + 0) * 260 + j] = v.x;
        Kst[(4 * d4 + 1) * 260 + j] = v.y;
        Kst[(4 * d4 + 2) * 260 + j] = v.z;
        Kst[(4 * d4 + 3) * 260 + j] = v.w;
      }
      __syncthreads();
#pragma unroll 8
      for (int d = 0; d < 32; ++d) {
        const float4 q4 = *(const float4*)&Qst[(dc * 32 + d) * 20 + (rg << 2)];
        const float4 k4 = *(const float4*)&Kst[d * 260 + (cg << 2)];
        acc[0][0] = fmaf(q4.x, k4.x, acc[0][0]);
        acc[0][1] = fmaf(q4.x, k4.y, acc[0][1]);
        acc[0][2] = fmaf(q4.x, k4.z, acc[0][2]);
        acc[0][3] = fmaf(q4.x, k4.w, acc[0][3]);
        acc[1][0] = fmaf(q4.y, k4.x, acc[1][0]);
        acc[1][1] = fmaf(q4.y, k4.y, acc[1][1]);
        acc[1][2] = fmaf(q4.y, k4.z, acc[1][2]);
        acc[1][3] = fmaf(q4.y, k4.w, acc[1][3]);
        acc[2][0] = fmaf(q4.z, k4.x, acc[2][0]);
        acc[2][1] = fmaf(q4.z, k4.y, acc[2][1]);
        acc[2][2] = fmaf(q4.z, k4.z, acc[2][2]);
        acc[2][3] = fmaf(q4.z, k4.w, acc[2][3]);
        acc[3][0] = fmaf(q4.w, k4.x, acc[3][0]);
        acc[3][1] = fmaf(q4.w, k4.y, acc[3][1]);
        acc[3][2] = fmaf(q4.w, k4.z, acc[3][2]);
        acc[3][3] = fmaf(q4.w, k4.w, acc[3][3]);
      }
    }

    // epilogue for this 256-col tile: mask, exp, write e, accumulate row sums
    const int j0 = (jt << 8) + (cg << 2);
#pragma unroll
    for (int i = 0; i < 4; ++i) {
      const int qi = row0 + (rg << 2) + i;
      const int wj = (qi * 4) / 5;  // window: j < wj masked
      int mv[4];
      if (byteMask) {
        const unsigned char* mr =
            (const unsigned char*)mask + ((size_t)b * Sn + qi) * Sn + j0;
        uchar4 mm = *(const uchar4*)mr;
        mv[0] = mm.x; mv[1] = mm.y; mv[2] = mm.z; mv[3] = mm.w;
      } else {
        const int* mr = (const int*)mask + ((size_t)b * Sn + qi) * Sn + j0;
        int4 mm = *(const int4*)mr;
        mv[0] = mm.x; mv[1] = mm.y; mv[2] = mm.z; mv[3] = mm.w;
      }
      float ev[4];
#pragma unroll
      for (int l = 0; l < 4; ++l) {
        const bool msk = (mv[l] != 0) || ((j0 + l) < wj);
        ev[l] = msk ? 0.f : __expf(acc[i][l] * SCALE);
        psum[i] += ev[l];
      }
      *(float4*)(attn + ((size_t)bh * Sn + qi) * Sn + j0) =
          make_float4(ev[0], ev[1], ev[2], ev[3]);
    }
  }

  // full-wave reduction: all 64 lanes of wave `rg` share the same 4 rows
#pragma unroll
  for (int off = 32; off > 0; off >>= 1)
#pragma unroll
    for (int i = 0; i < 4; ++i) psum[i] += __shfl_down(psum[i], off);
  if (cg == 0) {
#pragma unroll
    for (int i = 0; i < 4; ++i)
      rowsum[(size_t)bh * Sn + row0 + (rg << 2) + i] = psum[i];
  }
}

// ---------------------------------------------------------------------------
// Kernel 2: normalize attn in place (p = e / rowsum) and context = p @ V.
// Block: 256 thr, tile = 32 q-rows x DV=128; loop j in tiles of 64 with V
// staged in LDS. Thread: 4 rows x 4 dv (four float4 accumulators).
// ---------------------------------------------------------------------------
__global__ __launch_bounds__(256) void pv_kernel(
    const float* __restrict__ V, float* __restrict__ attn,
    const float* __restrict__ rowsum, float* __restrict__ ctx) {
  const int bh   = blockIdx.y;
  const int row0 = blockIdx.x << 5;   // 32 rows / block
  const int t    = threadIdx.x;
  const int rg   = t >> 5;            // 0..7 -> rows rg*4..+3
  const int dv4  = t & 31;            // float4 column of context

  __shared__ float4 Vs[64 * 32];      // [j][dv4], 32 KB
  __shared__ float  es[32 * 64];      // [r][j], 8 KB
  __shared__ float  inv[32];

  if (t < 32) inv[t] = 1.0f / rowsum[(size_t)bh * Sn + row0 + t];

  float4 acc[4];
#pragma unroll
  for (int i = 0; i < 4; ++i) acc[i] = make_float4(0.f, 0.f, 0.f, 0.f);

  const float4* Vg = (const float4*)(V + (size_t)bh * Sn * DVn);

  for (int jt = 0; jt < 32; ++jt) {
    __syncthreads();  // protects Vs/es reuse; also covers inv on first iter
    // stage V tile: rows j = jt*64..+63 (coalesced, conflict-free linear)
#pragma unroll
    for (int i = 0; i < 8; ++i) {
      int fid = t + (i << 8);
      Vs[fid] = Vg[(size_t)jt * 2048 + fid];
    }
    // stage e tile, normalize, write normalized attn back (in place)
#pragma unroll
    for (int i = 0; i < 2; ++i) {
      int fid = t + (i << 8);         // 0..511
      int r = fid >> 4, j4 = fid & 15;
      float4* ap =
          (float4*)(attn + ((size_t)bh * Sn + row0 + r) * Sn + (jt << 6)) + j4;
      float4 v = *ap;
      float iv = inv[r];
      v.x *= iv; v.y *= iv; v.z *= iv; v.w *= iv;
      *ap = v;
      *((float4*)&es[r * 64] + j4) = v;
    }
    __syncthreads();
#pragma unroll 8
    for (int j = 0; j < 64; ++j) {
      float4 v4 = Vs[(j << 5) + dv4];
      float p0 = es[((rg << 2) + 0) * 64 + j];
      float p1 = es[((rg << 2) + 1) * 64 + j];
      float p2 = es[((rg << 2) + 2) * 64 + j];
      float p3 = es[((rg << 2) + 3) * 64 + j];
      acc[0].x = fmaf(p0, v4.x, acc[0].x);
      acc[0].y = fmaf(p0, v4.y, acc[0].y);
      acc[0].z = fmaf(p0, v4.z, acc[0].z);
      acc[0].w = fmaf(p0, v4.w, acc[0].w);
      acc[1].x = fmaf(p1, v4.x, acc[1].x);
      acc[1].y = fmaf(p1, v4.y, acc[1].y);
      acc[1].z = fmaf(p1, v4.z, acc[1].z);
      acc[1].w = fmaf(p1, v4.w, acc[1].w);
      acc[2].x = fmaf(p2, v4.x, acc[2].x);
      acc[2].y = fmaf(p2, v4.y, acc[2].y);
      acc[2].z = fmaf(p2, v4.z, acc[2].z);
      acc[2].w = fmaf(p2, v4.w, acc[2].w);
      acc[3].x = fmaf(p3, v4.x, acc[3].x);
      acc[3].y = fmaf(p3, v4.y, acc[3].y);
      acc[3].z = fmaf(p3, v4.z, acc[3].z);
      acc[3].w = fmaf(p3, v4.w, acc[3].w);
    }
  }

#pragma unroll
  for (int i = 0; i < 4; ++i) {
    *((float4*)(ctx + ((size_t)bh * Sn + row0 + (rg << 2) + i) * DVn) + dv4) =
        acc[i];
  }
}

// ---------------------------------------------------------------------------
extern "C" void kernel_launch(void* const* d_in, const int* in_sizes, int n_in,
                              void* d_out, int out_size, void* d_ws,
                              size_t ws_size, hipStream_t stream) {
  const float* Q = (const float*)d_in[0];
  const float* K = (const float*)d_in[1];
  const float* V = (const float*)d_in[2];
  const void* mask = d_in[3];

  float* out  = (float*)d_out;
  float* ctx  = out;                                   // B*H*S*DV
  float* attn = out + (size_t)BHn * Sn * DVn;          // B*H*S*S

  float* rowsum = (float*)d_ws;                        // BH*S floats (256 KB)
  int*   mflag  = (int*)((char*)d_ws + (size_t)BHn * Sn * sizeof(float));

  detect_mask_kernel<<<1, 64, 0, stream>>>((const unsigned char*)mask, mflag);

  dim3 g1(Sn / 16, BHn);
  qk_exp_kernel<<<g1, 256, 0, stream>>>(Q, K, mask, mflag, attn, rowsum);

  dim3 g2(Sn / 32, BHn);
  pv_kernel<<<g2, 256, 0, stream>>>(V, attn, rowsum, ctx);
}

// Round 2
// 1417.460 us; speedup vs baseline: 1.2400x; 1.2400x over previous
//
#include <hip/hip_runtime.h>

#define Sn 2048
#define Dn 128
#define BHn 32
#define SCALE 0.08838834764831843f  // 1/sqrt(128)

using short8 = __attribute__((ext_vector_type(8))) short;
using f32x16 = __attribute__((ext_vector_type(16))) float;

__device__ inline short rne_bf16(float x) {
  union { float f; unsigned u; } c; c.f = x;
  unsigned r = c.u + 0x7FFFu + ((c.u >> 16) & 1u);
  return (short)(r >> 16);
}

__device__ inline f32x16 zero16() {
  f32x16 z;
#pragma unroll
  for (int i = 0; i < 16; ++i) z[i] = 0.f;
  return z;
}

// Mask dtype detector: int32 0/1 values have byte (4i+1)==0 always; byte bools
// are ~50% nonzero there. flag=1 -> byte mask, flag=0 -> 4-byte words.
__global__ void detect_mask_kernel(const unsigned char* __restrict__ m,
                                   int* __restrict__ flag) {
  if (threadIdx.x == 0) {
    int cnt = 0;
    for (int i = 0; i < 4096; ++i) cnt += (m[i * 4 + 1] != 0);
    *flag = (cnt > 0) ? 1 : 0;
  }
}

// ---------------------------------------------------------------------------
// Fused attention: per block = 128 q-rows of one (b,h).
// Pass 1: S = Q K^T (bf16 MFMA 32x32x16), e = exp(masked), rowsum in regs.
// Pass 2: recompute S, p = e * inv(rowsum), write attn fp32 once, PV MFMA.
// 4 waves x 32 q-rows. LDS: Kh bf16 chunk-plane layout (bank-balanced b128),
// Vs fp32 pad-132 (conflict-free scalar col reads), Ps per-wave swizzled.
// ---------------------------------------------------------------------------
__global__ __launch_bounds__(256, 2) void fused_attn_kernel(
    const float* __restrict__ Q, const float* __restrict__ K,
    const float* __restrict__ V, const void* __restrict__ mask,
    const int* __restrict__ mflag, float* __restrict__ attn,
    float* __restrict__ ctx) {
  const int bh = blockIdx.y, b = bh >> 4;
  const int row0 = blockIdx.x << 7;  // 128 rows / block
  const int t = threadIdx.x;
  const int w = t >> 6, lane = t & 63, h = lane >> 5, l32 = lane & 31;
  // mask read as bytes: for int32 0/1 the LSB byte equals the value.
  const int msh = (*mflag) ? 0 : 2;  // index shift: byte mask stride 1, word stride 4

  __shared__ short Kh[16 * 520];     // 16 k-chunk planes, pad 8 shorts/plane
  __shared__ float Vs[64 * 132];     // [j][dv], pad to 132
  __shared__ short Ps[4][1088];      // per-wave p tile 32x32 bf16, swizzled
  __shared__ float inv[128];

  // ---- persistent Q fragments (A-operand: m=l32 row, k = h*8 + j) ----
  short8 qh[8];
  {
    const float* qr = Q + (((size_t)bh << 11) + row0 + (w << 5) + l32) * Dn;
#pragma unroll
    for (int kc = 0; kc < 8; ++kc) {
      const float* p = qr + kc * 16 + h * 8;
      float4 a = *(const float4*)p, bb = *(const float4*)(p + 4);
      short8 v;
      v[0] = rne_bf16(a.x);  v[1] = rne_bf16(a.y);
      v[2] = rne_bf16(a.z);  v[3] = rne_bf16(a.w);
      v[4] = rne_bf16(bb.x); v[5] = rne_bf16(bb.y);
      v[6] = rne_bf16(bb.z); v[7] = rne_bf16(bb.w);
      qh[kc] = v;
    }
  }

  // per-reg row constants (C/D layout: row=(reg&3)+8*(reg>>2)+4*h, col=l32)
  int qi_r[16], wj_r[16];
#pragma unroll
  for (int reg = 0; reg < 16; ++reg) {
    int r = (reg & 3) + ((reg >> 2) << 3) + (h << 2);
    int qi = row0 + (w << 5) + r;
    qi_r[reg] = qi;
    wj_r[reg] = (qi << 2) / 5;  // window: j < wj masked
  }

  const float* Kg = K + (((size_t)bh << 11)) * Dn;
  const float* Vg = V + (((size_t)bh << 11)) * Dn;
  const unsigned char* maskB =
      (const unsigned char*)mask + ((((size_t)b << 11) * Sn) << msh);

  float psum[16];
#pragma unroll
  for (int i = 0; i < 16; ++i) psum[i] = 0.f;

  // ======================= PASS 1: row sums =======================
  for (int j0 = 0; j0 < Sn; j0 += 64) {
    __syncthreads();
#pragma unroll
    for (int i = 0; i < 4; ++i) {  // stage K chunk -> Kh (bf16)
      int task = t + (i << 8);
      int chunk = task & 15, j = task >> 4;
      const float* src = Kg + (size_t)(j0 + j) * Dn + chunk * 8;
      float4 a = *(const float4*)src, bb = *(const float4*)(src + 4);
      short8 v;
      v[0] = rne_bf16(a.x);  v[1] = rne_bf16(a.y);
      v[2] = rne_bf16(a.z);  v[3] = rne_bf16(a.w);
      v[4] = rne_bf16(bb.x); v[5] = rne_bf16(bb.y);
      v[6] = rne_bf16(bb.z); v[7] = rne_bf16(bb.w);
      *(short8*)&Kh[chunk * 520 + j * 8] = v;
    }
    __syncthreads();
#pragma unroll
    for (int jt = 0; jt < 2; ++jt) {
      f32x16 c = zero16();
#pragma unroll
      for (int kc = 0; kc < 8; ++kc) {
        short8 kb = *(const short8*)&Kh[((kc << 1) + h) * 520 + ((jt << 5) + l32) * 8];
        c = __builtin_amdgcn_mfma_f32_32x32x16_bf16(qh[kc], kb, c, 0, 0, 0);
      }
      const int jv = j0 + (jt << 5) + l32;
#pragma unroll
      for (int reg = 0; reg < 16; ++reg) {
        int mb = maskB[(size_t)((qi_r[reg] << 11) + jv) << msh];
        bool m = (mb != 0) | (jv < wj_r[reg]);
        float e = m ? 0.f : __expf(c[reg] * SCALE);
        psum[reg] += e;
      }
    }
  }

  // reduce row sums across the 32 columns held by each half-wave
#pragma unroll
  for (int reg = 0; reg < 16; ++reg) {
    float s = psum[reg];
    s += __shfl_xor(s, 1);  s += __shfl_xor(s, 2);  s += __shfl_xor(s, 4);
    s += __shfl_xor(s, 8);  s += __shfl_xor(s, 16);
    psum[reg] = s;
  }
  if (l32 == 0) {
#pragma unroll
    for (int reg = 0; reg < 16; ++reg) {
      int r = (reg & 3) + ((reg >> 2) << 3) + (h << 2);
      inv[(w << 5) + r] = 1.0f / psum[reg];
    }
  }

  // ======================= PASS 2: write attn + PV =======================
  f32x16 o[4];
#pragma unroll
  for (int i = 0; i < 4; ++i) o[i] = zero16();

  for (int j0 = 0; j0 < Sn; j0 += 64) {
    __syncthreads();
#pragma unroll
    for (int i = 0; i < 4; ++i) {  // stage K
      int task = t + (i << 8);
      int chunk = task & 15, j = task >> 4;
      const float* src = Kg + (size_t)(j0 + j) * Dn + chunk * 8;
      float4 a = *(const float4*)src, bb = *(const float4*)(src + 4);
      short8 v;
      v[0] = rne_bf16(a.x);  v[1] = rne_bf16(a.y);
      v[2] = rne_bf16(a.z);  v[3] = rne_bf16(a.w);
      v[4] = rne_bf16(bb.x); v[5] = rne_bf16(bb.y);
      v[6] = rne_bf16(bb.z); v[7] = rne_bf16(bb.w);
      *(short8*)&Kh[chunk * 520 + j * 8] = v;
    }
#pragma unroll
    for (int i = 0; i < 8; ++i) {  // stage V (fp32)
      int task = t + (i << 8);
      int j = task >> 5, dv4 = task & 31;
      *(float4*)&Vs[j * 132 + (dv4 << 2)] =
          *(const float4*)(Vg + (size_t)(j0 + j) * Dn + (dv4 << 2));
    }
    __syncthreads();
#pragma unroll
    for (int jt = 0; jt < 2; ++jt) {
      f32x16 c = zero16();
#pragma unroll
      for (int kc = 0; kc < 8; ++kc) {
        short8 kb = *(const short8*)&Kh[((kc << 1) + h) * 520 + ((jt << 5) + l32) * 8];
        c = __builtin_amdgcn_mfma_f32_32x32x16_bf16(qh[kc], kb, c, 0, 0, 0);
      }
      const int jv = j0 + (jt << 5) + l32;
#pragma unroll
      for (int reg = 0; reg < 16; ++reg) {
        int r = (reg & 3) + ((reg >> 2) << 3) + (h << 2);
        int qi = qi_r[reg];
        int mb = maskB[(size_t)((qi << 11) + jv) << msh];
        bool m = (mb != 0) | (jv < wj_r[reg]);
        float e = m ? 0.f : __expf(c[reg] * SCALE);
        float p = e * inv[(w << 5) + r];
        attn[((size_t)((bh << 11) + qi) << 11) + jv] = p;
        union { float f; unsigned u; } cc; cc.f = p;
        Ps[w][(r << 5) + ((r >> 2) << 3) + ((((l32 >> 3) ^ (r & 3))) << 3) + (l32 & 7)] =
            (short)(cc.u >> 16);
      }
      // PV: o[dvt] += P(32 x 32) * V(32 x 128-slice)
#pragma unroll
      for (int kc2 = 0; kc2 < 2; ++kc2) {
        short8 pa = *(const short8*)&Ps[w][(l32 << 5) + ((l32 >> 2) << 3) +
                                           ((((kc2 << 1) + h) ^ (l32 & 3)) << 3)];
        const int jl = (jt << 5) + (kc2 << 4) + (h << 3);
#pragma unroll
        for (int dvt = 0; dvt < 4; ++dvt) {
          const int dv = (dvt << 5) + l32;
          const float* vc = &Vs[jl * 132 + dv];
          unsigned a0 = __float_as_uint(vc[0 * 132]);
          unsigned a1 = __float_as_uint(vc[1 * 132]);
          unsigned a2 = __float_as_uint(vc[2 * 132]);
          unsigned a3 = __float_as_uint(vc[3 * 132]);
          unsigned a4 = __float_as_uint(vc[4 * 132]);
          unsigned a5 = __float_as_uint(vc[5 * 132]);
          unsigned a6 = __float_as_uint(vc[6 * 132]);
          unsigned a7 = __float_as_uint(vc[7 * 132]);
          union { unsigned u[4]; short8 s; } vb;
          vb.u[0] = __builtin_amdgcn_perm(a1, a0, 0x07060302);
          vb.u[1] = __builtin_amdgcn_perm(a3, a2, 0x07060302);
          vb.u[2] = __builtin_amdgcn_perm(a5, a4, 0x07060302);
          vb.u[3] = __builtin_amdgcn_perm(a7, a6, 0x07060302);
          o[dvt] = __builtin_amdgcn_mfma_f32_32x32x16_bf16(pa, vb.s, o[dvt], 0, 0, 0);
        }
      }
    }
  }

  // ---- write context ----
#pragma unroll
  for (int dvt = 0; dvt < 4; ++dvt) {
#pragma unroll
    for (int reg = 0; reg < 16; ++reg) {
      ctx[(((size_t)((bh << 11) + qi_r[reg])) << 7) + (dvt << 5) + l32] =
          o[dvt][reg];
    }
  }
}

// ---------------------------------------------------------------------------
extern "C" void kernel_launch(void* const* d_in, const int* in_sizes, int n_in,
                              void* d_out, int out_size, void* d_ws,
                              size_t ws_size, hipStream_t stream) {
  const float* Q = (const float*)d_in[0];
  const float* K = (const float*)d_in[1];
  const float* V = (const float*)d_in[2];
  const void* mask = d_in[3];

  float* out = (float*)d_out;
  float* ctx = out;                                  // B*H*S*DV
  float* attn = out + (size_t)BHn * Sn * (size_t)Dn; // B*H*S*S

  int* mflag = (int*)d_ws;

  detect_mask_kernel<<<1, 64, 0, stream>>>((const unsigned char*)mask, mflag);

  dim3 grid(Sn / 128, BHn);
  fused_attn_kernel<<<grid, 256, 0, stream>>>(Q, K, V, mask, mflag, attn, ctx);
}